// Round 1
// baseline (8331.403 us; speedup 1.0000x reference)
//
#include <hip/hip_runtime.h>
#include <hip/hip_bf16.h>
#include <cstdint>

#define TPB 256

__device__ __forceinline__ float lrelu_f(float y) { return y >= 0.f ? y : 0.2f * y; }

// ---------------------------------------------------------------------------
// Direct 3D conv: thread = one output spatial position (b,od,oh,ow),
// accumulates NOC consecutive output channels (chunk = blockIdx.y).
// Weight indices are wave-uniform -> scalar loads.
// ---------------------------------------------------------------------------
template<int NOC, bool ACT>
__global__ __launch_bounds__(TPB) void conv3d_direct(
    const float* __restrict__ in, const float* __restrict__ w, float* __restrict__ out,
    int B, int Ci, int Di, int Hi, int Wi,
    int Co, int kd, int kh, int kw,
    int sd, int sh, int sw, int pd, int ph, int pw,
    int Do, int Ho, int Wo)
{
    int flat = blockIdx.x * TPB + threadIdx.x;
    int total = B * Do * Ho * Wo;
    if (flat >= total) return;
    int ow = flat % Wo;
    int t = flat / Wo;
    int oh = t % Ho; t /= Ho;
    int od = t % Do;
    int b  = t / Do;
    int oc0 = blockIdx.y * NOC;
    int K = Ci * kd * kh * kw;
    const float* wb = w + (size_t)oc0 * K;

    float acc[NOC];
#pragma unroll
    for (int j = 0; j < NOC; ++j) acc[j] = 0.f;

    int id0 = od * sd - pd, ih0 = oh * sh - ph, iw0 = ow * sw - pw;
    for (int c = 0; c < Ci; ++c) {
        const float* ip = in + (size_t)(b * Ci + c) * Di * Hi * Wi;
        const float* wc = wb + c * kd * kh * kw;
        for (int kz = 0; kz < kd; ++kz) {
            int id = id0 + kz;
            if (id < 0 || id >= Di) continue;
            for (int ky = 0; ky < kh; ++ky) {
                int ih = ih0 + ky;
                if (ih < 0 || ih >= Hi) continue;
                const float* row = ip + ((size_t)id * Hi + ih) * Wi;
                const float* wr = wc + (kz * kh + ky) * kw;
                for (int kx = 0; kx < kw; ++kx) {
                    int iw = iw0 + kx;
                    if (iw < 0 || iw >= Wi) continue;
                    float v = row[iw];
#pragma unroll
                    for (int j = 0; j < NOC; ++j)
                        acc[j] += v * wr[(size_t)j * K + kx];
                }
            }
        }
    }
    size_t sp = (size_t)oh * Wo + ow;
    size_t obase = (((size_t)b * Co + oc0) * Do + od) * ((size_t)Ho * Wo) + sp;
    size_t ostride = (size_t)Do * Ho * Wo;
#pragma unroll
    for (int j = 0; j < NOC; ++j) {
        float y = acc[j];
        if (ACT) y = lrelu_f(y);
        out[obase + (size_t)j * ostride] = y;
    }
}

// ---------------------------------------------------------------------------
// BN stats, conv layout [B][C][S]: one block per channel. Writes scale/shift.
// ---------------------------------------------------------------------------
__global__ __launch_bounds__(TPB) void bn_stats(
    const float* __restrict__ x, const float* __restrict__ g, const float* __restrict__ bt,
    float* __restrict__ sc, float* __restrict__ sh, int B, int C, int S)
{
    int c = blockIdx.x;
    int tid = threadIdx.x;
    float s1 = 0.f, s2 = 0.f;
    for (int b = 0; b < B; ++b) {
        const float* p = x + ((size_t)b * C + c) * S;
        for (int i = tid; i < S; i += TPB) { float v = p[i]; s1 += v; s2 += v * v; }
    }
    __shared__ float r1[TPB], r2[TPB];
    r1[tid] = s1; r2[tid] = s2;
    __syncthreads();
    for (int o = TPB / 2; o > 0; o >>= 1) {
        if (tid < o) { r1[tid] += r1[tid + o]; r2[tid] += r2[tid + o]; }
        __syncthreads();
    }
    if (tid == 0) {
        float cnt = (float)B * (float)S;
        float mean = r1[0] / cnt;
        float var = r2[0] / cnt - mean * mean;
        float rs = rsqrtf(var + 1e-5f);
        float scl = g[c] * rs;
        sc[c] = scl;
        sh[c] = bt[c] - mean * scl;
    }
}

// BN stats, channel-last layout [Mrows][C]
__global__ __launch_bounds__(TPB) void bn_stats_cl(
    const float* __restrict__ x, const float* __restrict__ g, const float* __restrict__ bt,
    float* __restrict__ sc, float* __restrict__ sh, int Mrows, int C)
{
    int c = blockIdx.x;
    int tid = threadIdx.x;
    float s1 = 0.f, s2 = 0.f;
    for (int m = tid; m < Mrows; m += TPB) {
        float v = x[(size_t)m * C + c];
        s1 += v; s2 += v * v;
    }
    __shared__ float r1[TPB], r2[TPB];
    r1[tid] = s1; r2[tid] = s2;
    __syncthreads();
    for (int o = TPB / 2; o > 0; o >>= 1) {
        if (tid < o) { r1[tid] += r1[tid + o]; r2[tid] += r2[tid + o]; }
        __syncthreads();
    }
    if (tid == 0) {
        float cnt = (float)Mrows;
        float mean = r1[0] / cnt;
        float var = r2[0] / cnt - mean * mean;
        float rs = rsqrtf(var + 1e-5f);
        float scl = g[c] * rs;
        sc[c] = scl;
        sh[c] = bt[c] - mean * scl;
    }
}

// In-place BN apply + lrelu, conv layout [B][C][S]
__global__ __launch_bounds__(TPB) void bn_apply(
    float* __restrict__ x, const float* __restrict__ sc, const float* __restrict__ sh,
    int C, int S, long total)
{
    long i = (long)blockIdx.x * TPB + threadIdx.x;
    if (i >= total) return;
    int c = (int)((i / S) % C);
    float y = x[i] * sc[c] + sh[c];
    x[i] = lrelu_f(y);
}

// BN apply + lrelu, channel-last raw [(b*S+s)][C] -> conv layout out [B][C][S]
__global__ __launch_bounds__(TPB) void bn_apply_cl(
    const float* __restrict__ raw, const float* __restrict__ sc, const float* __restrict__ sh,
    float* __restrict__ out, int B, int C, int S)
{
    long total = (long)B * C * S;
    long i = (long)blockIdx.x * TPB + threadIdx.x;
    if (i >= total) return;
    int s = (int)(i % S);
    int c = (int)((i / S) % C);
    int b = (int)(i / ((long)S * C));
    float v = raw[((size_t)b * S + s) * C + c];
    float y = v * sc[c] + sh[c];
    out[i] = lrelu_f(y);
}

// ---------------------------------------------------------------------------
// Deformable trilinear sampling: block per (b, s), s in 32 = Do*Ho*Wo.
// Writes val[(b*32+s)][c*16+k]  (channel-last rows for the GEMM).
// x: enc3 [64][256][2][8][8]; off: [64][192][2][4][4], channel = (g*16+k)*3+comp
// ---------------------------------------------------------------------------
__global__ __launch_bounds__(TPB) void deform_val(
    const float* __restrict__ x, const float* __restrict__ off, float* __restrict__ val)
{
    int bs = blockIdx.x;
    int b = bs >> 5;
    int s = bs & 31;
    int dout = s >> 4, ho = (s >> 2) & 3, wo = s & 3;
    __shared__ float cw[64][8];
    __shared__ int cidx[64][8];
    int tid = threadIdx.x;
    if (tid < 64) {
        int gk = tid;               // g*16 + k
        int k = gk & 15;
        int ky = k >> 2, kx = k & 3;
        const float* op = off + ((size_t)b * 192 + gk * 3) * 32 + s;
        float pz = op[0]  + (float)dout;                 // sd=1, pd=0, kz=0
        float py = op[32] + (float)(ho * 2 - 1 + ky);    // sh=2, ph=1
        float px = op[64] + (float)(wo * 2 - 1 + kx);    // sw=2, pw=1
        float z0 = floorf(pz), y0 = floorf(py), x0 = floorf(px);
        float fz = pz - z0, fy = py - y0, fx = px - x0;
#pragma unroll
        for (int cz = 0; cz < 2; ++cz)
#pragma unroll
            for (int cy = 0; cy < 2; ++cy)
#pragma unroll
                for (int cx = 0; cx < 2; ++cx) {
                    float zc = z0 + cz, yc = y0 + cy, xc = x0 + cx;
                    bool valid = (zc >= 0.f) && (zc <= 1.f) &&
                                 (yc >= 0.f) && (yc <= 7.f) &&
                                 (xc >= 0.f) && (xc <= 7.f);
                    int zi = min(max((int)zc, 0), 1);
                    int yi = min(max((int)yc, 0), 7);
                    int xi = min(max((int)xc, 0), 7);
                    float wz = cz ? fz : 1.f - fz;
                    float wy = cy ? fy : 1.f - fy;
                    float wx = cx ? fx : 1.f - fx;
                    int ci = cz * 4 + cy * 2 + cx;
                    cw[gk][ci] = valid ? wz * wy * wx : 0.f;
                    cidx[gk][ci] = zi * 64 + yi * 8 + xi;
                }
    }
    __syncthreads();
    const float* xb = x + (size_t)b * 256 * 128;
    float* vout = val + (size_t)bs * 4096;
    for (int j = tid; j < 4096; j += TPB) {
        int c = j >> 4;
        int k = j & 15;
        int gk = ((c >> 6) << 4) | k;
        const float* xc = xb + (size_t)c * 128;
        float v = 0.f;
#pragma unroll
        for (int i = 0; i < 8; ++i) v += cw[gk][i] * xc[cidx[gk][i]];
        vout[j] = v;
    }
}

// ---------------------------------------------------------------------------
// fp32 GEMM: C[M][N] (+)= A[M][K] * Bw[N][K]^T, tiled 64x64xBK32,
// grid.z = K-split (atomicAdd into pre-zeroed C).
// M % 64 == 0, N % 64 == 0, klen % 32 == 0.
// ---------------------------------------------------------------------------
__global__ __launch_bounds__(TPB) void gemm_tn(
    const float* __restrict__ A, const float* __restrict__ Bw, float* __restrict__ C,
    int M, int N, int K, int klen)
{
    __shared__ float As[64][33];
    __shared__ float Bs[64][33];
    int tid = threadIdx.x;
    int m0 = blockIdx.x * 64;
    int n0 = blockIdx.y * 64;
    int k0 = blockIdx.z * klen;
    int kend = k0 + klen;
    int tx = tid & 15, ty = tid >> 4;
    int lr = tid >> 2;           // 0..63
    int lc = (tid & 3) * 8;      // 0,8,16,24
    float acc[4][4];
#pragma unroll
    for (int i = 0; i < 4; ++i)
#pragma unroll
        for (int j = 0; j < 4; ++j) acc[i][j] = 0.f;

    for (int kb = k0; kb < kend; kb += 32) {
        const float4* ap = (const float4*)(A + (size_t)(m0 + lr) * K + kb + lc);
        const float4* bp = (const float4*)(Bw + (size_t)(n0 + lr) * K + kb + lc);
        float4 a0 = ap[0], a1 = ap[1];
        float4 b0 = bp[0], b1 = bp[1];
        As[lr][lc + 0] = a0.x; As[lr][lc + 1] = a0.y; As[lr][lc + 2] = a0.z; As[lr][lc + 3] = a0.w;
        As[lr][lc + 4] = a1.x; As[lr][lc + 5] = a1.y; As[lr][lc + 6] = a1.z; As[lr][lc + 7] = a1.w;
        Bs[lr][lc + 0] = b0.x; Bs[lr][lc + 1] = b0.y; Bs[lr][lc + 2] = b0.z; Bs[lr][lc + 3] = b0.w;
        Bs[lr][lc + 4] = b1.x; Bs[lr][lc + 5] = b1.y; Bs[lr][lc + 6] = b1.z; Bs[lr][lc + 7] = b1.w;
        __syncthreads();
#pragma unroll
        for (int kk = 0; kk < 32; ++kk) {
            float av[4], bv[4];
#pragma unroll
            for (int i = 0; i < 4; ++i) av[i] = As[ty * 4 + i][kk];
#pragma unroll
            for (int j = 0; j < 4; ++j) bv[j] = Bs[tx * 4 + j][kk];
#pragma unroll
            for (int i = 0; i < 4; ++i)
#pragma unroll
                for (int j = 0; j < 4; ++j) acc[i][j] += av[i] * bv[j];
        }
        __syncthreads();
    }
#pragma unroll
    for (int i = 0; i < 4; ++i)
#pragma unroll
        for (int j = 0; j < 4; ++j)
            atomicAdd(&C[(size_t)(m0 + ty * 4 + i) * N + n0 + tx * 4 + j], acc[i][j]);
}

__global__ __launch_bounds__(TPB) void zero_f(float* __restrict__ p, long n)
{
    long i = (long)blockIdx.x * TPB + threadIdx.x;
    if (i < n) p[i] = 0.f;
}

// im2col for conv6: A6[(b*2+d)][c*16+hw] = enc4[((b*512+c)*2+d)*16+hw]
__global__ __launch_bounds__(TPB) void im2col6(
    const float* __restrict__ enc4, float* __restrict__ a6)
{
    int i = blockIdx.x * TPB + threadIdx.x;   // < 1048576
    int hw = i & 15;
    int c = (i >> 4) & 511;
    int m = i >> 13;
    int b = m >> 1;
    int d = m & 1;
    a6[i] = enc4[(((size_t)b * 512 + c) * 2 + d) * 16 + hw];
}

extern "C" void kernel_launch(void* const* d_in, const int* in_sizes, int n_in,
                              void* d_out, int out_size, void* d_ws, size_t ws_size,
                              hipStream_t stream)
{
    (void)in_sizes; (void)n_in; (void)out_size; (void)ws_size;
    const float* x_in  = (const float*)d_in[0];
    const float* w1    = (const float*)d_in[1];
    const float* w2    = (const float*)d_in[2];
    const float* w3    = (const float*)d_in[3];
    const float* w4    = (const float*)d_in[4];
    const float* w_off = (const float*)d_in[5];
    const float* w5    = (const float*)d_in[6];
    const float* w6    = (const float*)d_in[7];
    const float* g2 = (const float*)d_in[8];  const float* b2 = (const float*)d_in[9];
    const float* g3 = (const float*)d_in[10]; const float* b3 = (const float*)d_in[11];
    const float* g4 = (const float*)d_in[12]; const float* b4 = (const float*)d_in[13];
    const float* g5 = (const float*)d_in[14]; const float* b5 = (const float*)d_in[15];
    const float* g6 = (const float*)d_in[16]; const float* b6 = (const float*)d_in[17];

    float* out = (float*)d_out;
    float* enc0 = out;                 // [64][32][4][64][64]  33554432
    float* enc1 = out + 33554432;      // [64][64][3][32][32]  12582912
    float* enc2 = out + 46137344;      // [64][128][2][16][16]  4194304
    float* enc3 = out + 50331648;      // [64][256][2][8][8]    2097152
    float* enc4 = out + 52428800;      // [64][512][2][4][4]    1048576
    float* enc5 = out + 53477376;      // [64][512][2][1][1]      65536

    float* ws   = (float*)d_ws;
    float* offb = ws;                  // 393216  [64][192][2][4][4]
    float* val  = ws + 393216;         // 8388608 [2048][4096]
    float* raw5 = ws + 8781824;        // 1048576 [2048][512]
    float* raw6 = ws + 9830400;        // 65536   [128][512]
    float* a6   = ws + 9895936;        // 1048576 [128][8192]
    float* sc   = ws + 10944512;       // 512
    float* sh   = ws + 10945024;       // 512

    // ---- Layer 1: conv1 + lrelu (no BN) -> enc0
    conv3d_direct<32, true><<<dim3(4096, 1), TPB, 0, stream>>>(
        x_in, w1, enc0, 64, 3, 8, 128, 128, 32, 4, 4, 4, 2, 2, 2, 1, 1, 1, 4, 64, 64);

    // ---- Layer 2: conv2 -> enc1 raw; BN+lrelu in place
    conv3d_direct<16, false><<<dim3(768, 4), TPB, 0, stream>>>(
        enc0, w2, enc1, 64, 32, 4, 64, 64, 64, 2, 4, 4, 1, 2, 2, 0, 1, 1, 3, 32, 32);
    bn_stats<<<64, TPB, 0, stream>>>(enc1, g2, b2, sc, sh, 64, 64, 3072);
    bn_apply<<<49152, TPB, 0, stream>>>(enc1, sc, sh, 64, 3072, 12582912L);

    // ---- Layer 3
    conv3d_direct<16, false><<<dim3(128, 8), TPB, 0, stream>>>(
        enc1, w3, enc2, 64, 64, 3, 32, 32, 128, 2, 4, 4, 1, 2, 2, 0, 1, 1, 2, 16, 16);
    bn_stats<<<128, TPB, 0, stream>>>(enc2, g3, b3, sc, sh, 64, 128, 512);
    bn_apply<<<16384, TPB, 0, stream>>>(enc2, sc, sh, 128, 512, 4194304L);

    // ---- Layer 4
    conv3d_direct<16, false><<<dim3(32, 16), TPB, 0, stream>>>(
        enc2, w4, enc3, 64, 128, 2, 16, 16, 256, 1, 4, 4, 1, 2, 2, 0, 1, 1, 2, 8, 8);
    bn_stats<<<256, TPB, 0, stream>>>(enc3, g4, b4, sc, sh, 64, 256, 128);
    bn_apply<<<8192, TPB, 0, stream>>>(enc3, sc, sh, 256, 128, 2097152L);

    // ---- Offsets conv (no BN, no act) -> ws
    conv3d_direct<16, false><<<dim3(8, 12), TPB, 0, stream>>>(
        enc3, w_off, offb, 64, 256, 2, 8, 8, 192, 1, 4, 4, 1, 2, 2, 0, 1, 1, 2, 4, 4);

    // ---- Deformable conv: sample -> val, then GEMM val x w5^T
    deform_val<<<2048, TPB, 0, stream>>>(enc3, offb, val);
    zero_f<<<4352, TPB, 0, stream>>>(raw5, 1114112L);   // raw5 + raw6 contiguous
    gemm_tn<<<dim3(32, 8, 2), TPB, 0, stream>>>(val, w5, raw5, 2048, 512, 4096, 2048);
    bn_stats_cl<<<512, TPB, 0, stream>>>(raw5, g5, b5, sc, sh, 2048, 512);
    bn_apply_cl<<<4096, TPB, 0, stream>>>(raw5, sc, sh, enc4, 64, 512, 32);

    // ---- Layer 6: im2col + GEMM (K-split 8)
    im2col6<<<4096, TPB, 0, stream>>>(enc4, a6);
    gemm_tn<<<dim3(2, 8, 8), TPB, 0, stream>>>(a6, w6, raw6, 128, 512, 8192, 1024);
    bn_stats_cl<<<512, TPB, 0, stream>>>(raw6, g6, b6, sc, sh, 128, 512);
    bn_apply_cl<<<256, TPB, 0, stream>>>(raw6, sc, sh, enc5, 64, 512, 2);
}

// Round 3
// 809.982 us; speedup vs baseline: 10.2859x; 10.2859x over previous
//
#include <hip/hip_runtime.h>
#include <hip/hip_bf16.h>
#include <cstdint>

typedef short bf16x8 __attribute__((ext_vector_type(8)));
typedef float f32x4 __attribute__((ext_vector_type(4)));

__device__ __forceinline__ float lrelu_f(float y) { return y >= 0.f ? y : 0.2f * y; }
__device__ __forceinline__ float b2f(unsigned short u) {
    union { unsigned int i; float f; } v; v.i = ((unsigned int)u) << 16; return v.f;
}
__device__ __forceinline__ unsigned short f2b(float f) {
    union { unsigned int i; float f; } v; v.f = f;
    unsigned int r = v.i + 0x7FFFu + ((v.i >> 16) & 1u);
    return (unsigned short)(r >> 16);
}

// ---------------------------------------------------------------------------
// x (fp32 NCDHW [64][3][8][128][128]) -> bf16 CL [64][8][128][128][4] (c pad 3->4)
// ---------------------------------------------------------------------------
__global__ __launch_bounds__(256) void xin_cl_k(const float* __restrict__ x,
                                                unsigned short* __restrict__ xc)
{
    int i = blockIdx.x * 256 + threadIdx.x;       // exactly 33554432 threads
    int c = i & 3, w = (i >> 2) & 127, h = (i >> 9) & 127, d = (i >> 16) & 7, b = i >> 19;
    float v = (c < 3) ? x[(((size_t)b * 3 + c) * 8 + d) * 16384 + h * 128 + w] : 0.f;
    xc[i] = f2b(v);
}

// W fp32 [O][Cin][Tap] -> bf16 [O][Tap][Cip] (c padded)
__global__ __launch_bounds__(256) void repack_w(const float* __restrict__ w,
                                                unsigned short* __restrict__ wp,
                                                int Cin, int Tap, int Cip, long total)
{
    long i = (long)blockIdx.x * 256 + threadIdx.x;
    if (i >= total) return;
    int c = (int)(i % Cip);
    long t1 = i / Cip;
    int t = (int)(t1 % Tap);
    long o = t1 / Tap;
    wp[i] = (c < Cin) ? f2b(w[((size_t)o * Cin + c) * Tap + t]) : (unsigned short)0;
}

__global__ __launch_bounds__(256) void f2bk(const float* __restrict__ in,
                                            unsigned short* __restrict__ o, long n)
{
    long i = (long)blockIdx.x * 256 + threadIdx.x;
    if (i < n) o[i] = f2b(in[i]);
}

// ---------------------------------------------------------------------------
// Implicit-GEMM MFMA kernel. C[M][N] = A[M][K] * Bw[N][K]^T, bf16 in, fp32 acc.
// Tile 128 x BN, 4 waves, K-chunk 32, mfma_f32_16x16x32_bf16.
// AMODE 0: A is plain row-major bf16 [M][K]
// AMODE 1: A is CL activations; K order [tap][c], Ci%32==0, row=(b,od,oh,ow)
// AMODE 2: conv1 special: 4x4x4 kernel, Cip=4, K order [tap][c4]
// EPI 0: bf16 store to Cout[M][N]; EPI 1: fp32 store; EPI 2: fp32 atomicAdd (split-K)
// ---------------------------------------------------------------------------
template<int BN, int AMODE, int EPI>
__global__ __launch_bounds__(256) void igemm(
    const unsigned short* __restrict__ A, const unsigned short* __restrict__ Bw,
    void* __restrict__ Cout,
    int M, int N, int K, int klen,
    int Ci, int Di, int Hi, int Wi,
    int kd, int kh, int kw,
    int sd, int sh_, int sw_, int pd, int ph_, int pw_,
    int Do, int Ho, int Wo)
{
    constexpr int NF = BN / 32;
    constexpr int WN = 16 * NF;
    constexpr int NBU = (BN * 4 + 255) / 256;
    __shared__ __align__(16) unsigned short As[4][128][8];
    __shared__ __align__(16) unsigned short Bs[4][BN][8];
    const int tid = threadIdx.x;
    const int m0 = blockIdx.x * 128;
    const int n0 = blockIdx.y * BN;
    const int k0 = blockIdx.z * klen;          // nonzero only for AMODE 0
    const int kend = min(K, k0 + klen);

    // B staging precompute
    size_t bsrc[NBU];
    unsigned short* bdst[NBU];
#pragma unroll
    for (int i = 0; i < NBU; ++i) {
        int u = tid + i * 256;
        int row = u >> 2, s = u & 3;
        if (BN * 4 >= 256 || u < BN * 4) {
            bsrc[i] = (size_t)(n0 + row) * K + s * 8;
            bdst[i] = &Bs[s][row][0];
        }
    }

    // A staging precompute
    constexpr int NAU = (AMODE == 2) ? 4 : 2;
    size_t asz[2];
    int asrc[NAU];
    unsigned long long amask[NAU];
    unsigned short* adst[NAU];

    if constexpr (AMODE == 0) {
#pragma unroll
        for (int i = 0; i < 2; ++i) {
            int u = tid + i * 256;
            int r = u >> 2, s = u & 3;
            asz[i] = (size_t)(m0 + r) * K + s * 8;
            adst[i] = &As[s][r][0];
        }
    } else {
#pragma unroll
        for (int i = 0; i < NAU; ++i) {
            int u = tid + i * 256;
            int r = (AMODE == 2) ? (u >> 3) : (u >> 2);
            int m = m0 + r;
            int ow = m % Wo; int t1 = m / Wo;
            int oh = t1 % Ho; t1 /= Ho;
            int od = t1 % Do; int b = t1 / Do;
            int id0 = od * sd - pd, ih0 = oh * sh_ - ph_, iw0 = ow * sw_ - pw_;
            unsigned long long xm = 0ull, yx = 0ull, mask = 0ull;
            for (int p = 0; p < kw; ++p) if ((unsigned)(iw0 + p) < (unsigned)Wi) xm |= 1ull << p;
            for (int p = 0; p < kh; ++p) if ((unsigned)(ih0 + p) < (unsigned)Hi) yx |= xm << (p * kw);
            for (int p = 0; p < kd; ++p) if ((unsigned)(id0 + p) < (unsigned)Di) mask |= yx << (p * kh * kw);
            amask[i] = mask;
            int bsp = ((b * Di + id0) * Hi + ih0) * Wi + iw0;
            if constexpr (AMODE == 1) {
                int s = u & 3;
                asrc[i] = bsp * Ci + s * 8;
                adst[i] = &As[s][r][0];
            } else {
                int j = u & 7;
                asrc[i] = (bsp + (j >> 2) * Wi + (j & 3)) * 4;
                adst[i] = &As[j >> 1][r][(j & 1) * 4];
            }
        }
    }

    f32x4 acc[4][NF];
#pragma unroll
    for (int i = 0; i < 4; ++i)
#pragma unroll
        for (int j = 0; j < NF; ++j) acc[i][j] = (f32x4){0.f, 0.f, 0.f, 0.f};

    const int lane = tid & 63, wv = tid >> 6;
    const int wm = wv >> 1, wn = wv & 1;
    const int kg = lane >> 4, fr = lane & 15;

    // uniform k-walk state (AMODE 1), k0 == 0 there
    int c0 = 0, kx = 0, ky = 0, tap = 0, doff = 0;

    for (int k = k0; k < kend; k += 32) {
        // ---- B stage
#pragma unroll
        for (int i = 0; i < NBU; ++i)
            if (BN * 4 >= 256 || tid + i * 256 < BN * 4) {
                uint4 v = *(const uint4*)&Bw[bsrc[i] + k];
                *(uint4*)bdst[i] = v;
            }
        // ---- A stage
        if constexpr (AMODE == 0) {
#pragma unroll
            for (int i = 0; i < 2; ++i) {
                uint4 v = *(const uint4*)&A[asz[i] + k];
                *(uint4*)adst[i] = v;
            }
        } else if constexpr (AMODE == 1) {
            int dofe = doff * Ci + c0;
#pragma unroll
            for (int i = 0; i < 2; ++i) {
                uint4 v = {0u, 0u, 0u, 0u};
                if ((amask[i] >> tap) & 1ull)
                    v = *(const uint4*)&A[(size_t)(asrc[i] + dofe)];
                *(uint4*)adst[i] = v;
            }
        } else {
            int kz = k >> 6;
            int U4 = (kz * (Hi * Wi) + ((k >> 5) & 1) * 2 * Wi) * 4;
            int tap0 = k >> 2;
#pragma unroll
            for (int i = 0; i < 4; ++i) {
                int j = (tid + i * 256) & 7;
                uint2 v = {0u, 0u};
                if ((amask[i] >> (tap0 + j)) & 1ull)
                    v = *(const uint2*)&A[(size_t)(asrc[i] + U4)];
                *(uint2*)adst[i] = v;
            }
        }
        __syncthreads();
        bf16x8 af[4], bfr[NF];
#pragma unroll
        for (int mi = 0; mi < 4; ++mi)
            af[mi] = *(const bf16x8*)&As[kg][wm * 64 + mi * 16 + fr][0];
#pragma unroll
        for (int ni = 0; ni < NF; ++ni)
            bfr[ni] = *(const bf16x8*)&Bs[kg][wn * WN + ni * 16 + fr][0];
#pragma unroll
        for (int mi = 0; mi < 4; ++mi)
#pragma unroll
            for (int ni = 0; ni < NF; ++ni)
                acc[mi][ni] = __builtin_amdgcn_mfma_f32_16x16x32_bf16(af[mi], bfr[ni], acc[mi][ni], 0, 0, 0);
        __syncthreads();
        if constexpr (AMODE == 1) {
            c0 += 32;
            if (c0 >= Ci) {
                c0 = 0; ++tap; ++kx; ++doff;
                if (kx == kw) {
                    kx = 0; doff += Wi - kw; ++ky;
                    if (ky == kh) { ky = 0; doff += (Hi - kh) * Wi; }
                }
            }
        }
    }
    // ---- epilogue: D row=(lane>>4)*4+reg, col=lane&15
    const int rb = m0 + wm * 64 + (lane >> 4) * 4;
    const int cb = n0 + wn * WN + fr;
#pragma unroll
    for (int mi = 0; mi < 4; ++mi)
#pragma unroll
        for (int ni = 0; ni < NF; ++ni)
#pragma unroll
            for (int rg = 0; rg < 4; ++rg) {
                size_t idx = (size_t)(rb + mi * 16 + rg) * N + cb + ni * 16;
                float vv = acc[mi][ni][rg];
                if constexpr (EPI == 0) ((unsigned short*)Cout)[idx] = f2b(vv);
                else if constexpr (EPI == 1) ((float*)Cout)[idx] = vv;
                else atomicAdd((float*)Cout + idx, vv);
            }
}

// ---------------------------------------------------------------------------
// BN partial sums over bf16 CL [Mrows][C] -> sums[0..C)=Σx, sums[C..2C)=Σx²
// ---------------------------------------------------------------------------
__global__ __launch_bounds__(256) void bn_sums(const unsigned short* __restrict__ x,
                                               float* __restrict__ sums,
                                               long totalSlots, int C)
{
    const int tid = threadIdx.x;
    long gid = (long)blockIdx.x * 256 + tid;
    long stride = (long)gridDim.x * 256;     // stride*8 % C == 0 for C in {32..512}
    float s1[8], s2[8];
#pragma unroll
    for (int j = 0; j < 8; ++j) { s1[j] = 0.f; s2[j] = 0.f; }
    for (long s = gid; s < totalSlots; s += stride) {
        uint4 v = *(const uint4*)&x[s * 8];
        const unsigned short* pv = (const unsigned short*)&v;
#pragma unroll
        for (int j = 0; j < 8; ++j) { float f = b2f(pv[j]); s1[j] += f; s2[j] += f * f; }
    }
    __shared__ float r1[2048], r2[2048];
#pragma unroll
    for (int j = 0; j < 8; ++j) { r1[tid * 8 + j] = s1[j]; r2[tid * 8 + j] = s2[j]; }
    __syncthreads();
    int G = C >> 3;
    for (int c = tid; c < C; c += 256) {
        int grp = c >> 3, j = c & 7;
        float a = 0.f, b = 0.f;
        for (int th = grp; th < 256; th += G) { a += r1[th * 8 + j]; b += r2[th * 8 + j]; }
        atomicAdd(&sums[c], a);
        atomicAdd(&sums[C + c], b);
    }
}

__global__ __launch_bounds__(256) void bn_fin(const float* __restrict__ sums,
                                              const float* __restrict__ g, const float* __restrict__ bt,
                                              float* __restrict__ sc, float* __restrict__ sh,
                                              int C, float invcnt)
{
    int c = blockIdx.x * 256 + threadIdx.x;
    if (c >= C) return;
    float mean = sums[c] * invcnt;
    float var = sums[C + c] * invcnt - mean * mean;
    float rs = rsqrtf(var + 1e-5f);
    float scl = g[c] * rs;
    sc[c] = scl;
    sh[c] = bt[c] - mean * scl;
}

// ---------------------------------------------------------------------------
// Fused BN-apply + lrelu: bf16 CL in-place, plus fp32 NCDHW via LDS transpose.
// Tile: 64 rows x TC channels. Grid (Mrows/64, C/TC). TC in {32,64}.
// ---------------------------------------------------------------------------
template<bool BNE>
__global__ __launch_bounds__(256) void bn_apply_t(
    unsigned short* __restrict__ x, const float* __restrict__ sc, const float* __restrict__ sh,
    float* __restrict__ outN, int C, int TC, int S)
{
    __shared__ __align__(16) float T[64][68];
    const int tid = threadIdx.x;
    const long m0 = (long)blockIdx.x * 64;
    const int c0 = blockIdx.y * TC;
    const int spr = TC >> 3;                  // 16B slots per row: 4 or 8
    const int lg = (spr == 8) ? 3 : 2;
    const int tot = 64 * spr;
    for (int u = tid; u < tot; u += 256) {
        int r = u >> lg, sl = u & (spr - 1);
        size_t idx = (size_t)(m0 + r) * C + c0 + sl * 8;
        uint4 v = *(uint4*)&x[idx];
        unsigned short* pv = (unsigned short*)&v;
#pragma unroll
        for (int j = 0; j < 8; ++j) {
            int c = c0 + sl * 8 + j;
            float f = b2f(pv[j]);
            if (BNE) f = f * sc[c] + sh[c];
            f = lrelu_f(f);
            pv[j] = f2b(f);
            T[sl * 8 + j][r] = f;
        }
        *(uint4*)&x[idx] = v;
    }
    __syncthreads();
    const int tpc = 256 / TC;                 // threads per column
    const int rpt = 64 / tpc;
    int cl = tid / tpc;
    int r0 = (tid % tpc) * rpt;
    int c = c0 + cl;
    if ((S & 63) == 0) {
        long b = m0 / S;
        long s0 = m0 - b * S;
        float* op = outN + ((size_t)b * C + c) * S + s0 + r0;
        for (int r = 0; r < rpt; r += 4)
            *(float4*)(op + r) = *(float4*)&T[cl][r0 + r];
    } else {
        for (int r = 0; r < rpt; ++r) {
            long m = m0 + r0 + r;
            long b = m / S, s = m - b * S;
            outN[((size_t)b * C + c) * S + s] = T[cl][r0 + r];
        }
    }
}

// ---------------------------------------------------------------------------
// Deformable trilinear sampling: block per (b, s), s in 32 output positions.
// x: enc3 CL bf16 [64][128 sp][256]; off: fp32 [2048][192]; val bf16 [2048][16*256]
// val[m][tap*256 + c]
// ---------------------------------------------------------------------------
__global__ __launch_bounds__(256) void deform_val(
    const unsigned short* __restrict__ xcl, const float* __restrict__ offc,
    unsigned short* __restrict__ val)
{
    int bs = blockIdx.x;
    int b = bs >> 5, s = bs & 31;
    int od = s >> 4, oh = (s >> 2) & 3, ow = s & 3;
    __shared__ float cw[64][8];
    __shared__ int cidx[64][8];
    int tid = threadIdx.x;
    if (tid < 64) {
        int gk = tid, k = gk & 15;
        int ky = k >> 2, kx = k & 3;
        const float* op = offc + (size_t)bs * 192 + gk * 3;
        float pz = op[0] + (float)od;
        float py = op[1] + (float)(oh * 2 - 1 + ky);
        float px = op[2] + (float)(ow * 2 - 1 + kx);
        float z0 = floorf(pz), y0 = floorf(py), x0 = floorf(px);
        float fz = pz - z0, fy = py - y0, fx = px - x0;
#pragma unroll
        for (int ci = 0; ci < 8; ++ci) {
            int cz = ci >> 2, cy = (ci >> 1) & 1, cx = ci & 1;
            float zc = z0 + cz, yc = y0 + cy, xc = x0 + cx;
            bool ok = zc >= 0.f && zc <= 1.f && yc >= 0.f && yc <= 7.f && xc >= 0.f && xc <= 7.f;
            int zi = min(max((int)zc, 0), 1);
            int yi = min(max((int)yc, 0), 7);
            int xi = min(max((int)xc, 0), 7);
            float wz = cz ? fz : 1.f - fz;
            float wy = cy ? fy : 1.f - fy;
            float wx = cx ? fx : 1.f - fx;
            cw[gk][ci] = ok ? wz * wy * wx : 0.f;
            cidx[gk][ci] = (zi * 8 + yi) * 8 + xi;
        }
    }
    __syncthreads();
    const unsigned short* xb = xcl + (size_t)b * 128 * 256;
    unsigned short* vo = val + (size_t)bs * 4096;
    for (int j = tid; j < 4096; j += 256) {
        int c = j & 255, tap = j >> 8;
        int gk = ((c >> 6) << 4) | tap;
        float v = 0.f;
#pragma unroll
        for (int i = 0; i < 8; ++i)
            v += cw[gk][i] * b2f(xb[(size_t)cidx[gk][i] * 256 + c]);
        vo[j] = f2b(v);
    }
}

// ---------------------------------------------------------------------------
extern "C" void kernel_launch(void* const* d_in, const int* in_sizes, int n_in,
                              void* d_out, int out_size, void* d_ws, size_t ws_size,
                              hipStream_t stream)
{
    (void)in_sizes; (void)n_in; (void)out_size; (void)ws_size;
    const float* x     = (const float*)d_in[0];
    const float* w1    = (const float*)d_in[1];
    const float* w2    = (const float*)d_in[2];
    const float* w3    = (const float*)d_in[3];
    const float* w4    = (const float*)d_in[4];
    const float* w_off = (const float*)d_in[5];
    const float* w5    = (const float*)d_in[6];
    const float* w6    = (const float*)d_in[7];
    const float* g2 = (const float*)d_in[8];  const float* b2 = (const float*)d_in[9];
    const float* g3 = (const float*)d_in[10]; const float* b3 = (const float*)d_in[11];
    const float* g4 = (const float*)d_in[12]; const float* b4 = (const float*)d_in[13];
    const float* g5 = (const float*)d_in[14]; const float* b5 = (const float*)d_in[15];
    const float* g6 = (const float*)d_in[16]; const float* b6 = (const float*)d_in[17];

    float* out = (float*)d_out;
    float* enc0 = out;
    float* enc1 = out + 33554432;
    float* enc2 = out + 46137344;
    float* enc3 = out + 50331648;
    float* enc4 = out + 52428800;
    float* enc5 = out + 53477376;

    // workspace layout (needs ~103 MiB)
    char* W = (char*)d_ws;
    unsigned short* w1p  = (unsigned short*)(W + 0);
    unsigned short* w2p  = (unsigned short*)(W + 16384);
    unsigned short* w3p  = (unsigned short*)(W + 147456);
    unsigned short* w4p  = (unsigned short*)(W + 671744);
    unsigned short* wofp = (unsigned short*)(W + 1720320);
    unsigned short* w5p  = (unsigned short*)(W + 3293184);
    unsigned short* w6p  = (unsigned short*)(W + 7487488);
    float* sums          = (float*)(W + 15876096);
    float* sc            = (float*)(W + 15880192);
    float* sh            = (float*)(W + 15882240);
    float* offc          = (float*)(W + 15884288);
    unsigned short* xcl  = (unsigned short*)(W + 17457152);   // dies after conv1
    unsigned short* e1c  = (unsigned short*)(W + 17457152);   // reuses xcl region
    unsigned short* e2c  = (unsigned short*)(W + 42622976);
    unsigned short* e3c  = (unsigned short*)(W + 51011584);
    unsigned short* e0c  = (unsigned short*)(W + 84566016);   // dies after conv2
    unsigned short* valb = (unsigned short*)(W + 84566016);   // reuses e0c region
    float* raw5          = (float*)(W + 101343232);
    unsigned short* e4c  = (unsigned short*)(W + 105537536);
    float* raw6          = (float*)(W + 107634688);
    unsigned short* e5c  = (unsigned short*)(W + 107896832);

    // ---- prep: input + weight repacks to bf16
    xin_cl_k<<<131072, 256, 0, stream>>>(x, xcl);
    repack_w<<<32, 256, 0, stream>>>(w1, w1p, 3, 64, 4, 8192L);
    repack_w<<<256, 256, 0, stream>>>(w2, w2p, 32, 32, 32, 65536L);
    repack_w<<<1024, 256, 0, stream>>>(w3, w3p, 64, 32, 64, 262144L);
    repack_w<<<2048, 256, 0, stream>>>(w4, w4p, 128, 16, 128, 524288L);
    repack_w<<<3072, 256, 0, stream>>>(w_off, wofp, 256, 16, 256, 786432L);
    repack_w<<<8192, 256, 0, stream>>>(w5, w5p, 256, 16, 256, 2097152L);
    repack_w<<<16384, 256, 0, stream>>>(w6, w6p, 512, 16, 512, 4194304L);

    // ---- L1: conv1 (4x4x4 s2 p1) -> e0c raw; lrelu + NCDHW out
    igemm<32, 2, 0><<<dim3(8192, 1, 1), 256, 0, stream>>>(
        xcl, w1p, e0c, 1048576, 32, 256, 256,
        4, 8, 128, 128, 4, 4, 4, 2, 2, 2, 1, 1, 1, 4, 64, 64);
    bn_apply_t<false><<<dim3(16384, 1), 256, 0, stream>>>(e0c, nullptr, nullptr, enc0, 32, 32, 16384);

    // ---- L2
    igemm<64, 1, 0><<<dim3(1536, 1, 1), 256, 0, stream>>>(
        e0c, w2p, e1c, 196608, 64, 1024, 1024,
        32, 4, 64, 64, 2, 4, 4, 1, 2, 2, 0, 1, 1, 3, 32, 32);
    hipMemsetAsync(sums, 0, 4096, stream);
    bn_sums<<<256, 256, 0, stream>>>(e1c, sums, 1572864L, 64);
    bn_fin<<<1, 256, 0, stream>>>(sums, g2, b2, sc, sh, 64, 1.f / 196608.f);
    bn_apply_t<true><<<dim3(3072, 1), 256, 0, stream>>>(e1c, sc, sh, enc1, 64, 64, 3072);

    // ---- L3
    igemm<128, 1, 0><<<dim3(256, 1, 1), 256, 0, stream>>>(
        e1c, w3p, e2c, 32768, 128, 2048, 2048,
        64, 3, 32, 32, 2, 4, 4, 1, 2, 2, 0, 1, 1, 2, 16, 16);
    hipMemsetAsync(sums, 0, 4096, stream);
    bn_sums<<<256, 256, 0, stream>>>(e2c, sums, 524288L, 128);
    bn_fin<<<1, 256, 0, stream>>>(sums, g3, b3, sc, sh, 128, 1.f / 32768.f);
    bn_apply_t<true><<<dim3(512, 2), 256, 0, stream>>>(e2c, sc, sh, enc2, 128, 64, 512);

    // ---- L4
    igemm<256, 1, 0><<<dim3(64, 1, 1), 256, 0, stream>>>(
        e2c, w4p, e3c, 8192, 256, 2048, 2048,
        128, 2, 16, 16, 1, 4, 4, 1, 2, 2, 0, 1, 1, 2, 8, 8);
    hipMemsetAsync(sums, 0, 4096, stream);
    bn_sums<<<256, 256, 0, stream>>>(e3c, sums, 262144L, 256);
    bn_fin<<<1, 256, 0, stream>>>(sums, g4, b4, sc, sh, 256, 1.f / 8192.f);
    bn_apply_t<true><<<dim3(128, 4), 256, 0, stream>>>(e3c, sc, sh, enc3, 256, 64, 128);

    // ---- offset conv (no BN, no act), fp32 CL out
    igemm<192, 1, 1><<<dim3(16, 1, 1), 256, 0, stream>>>(
        e3c, wofp, offc, 2048, 192, 4096, 4096,
        256, 2, 8, 8, 1, 4, 4, 1, 2, 2, 0, 1, 1, 2, 4, 4);

    // ---- deformable sampling + GEMM (split-K 2, fp32 atomic)
    deform_val<<<2048, 256, 0, stream>>>(e3c, offc, valb);
    hipMemsetAsync(raw5, 0, 4194304, stream);
    igemm<64, 0, 2><<<dim3(16, 8, 2), 256, 0, stream>>>(
        valb, w5p, raw5, 2048, 512, 4096, 2048,
        0, 0, 0, 0, 1, 1, 1, 1, 1, 1, 0, 0, 0, 1, 1, 1);
    f2bk<<<4096, 256, 0, stream>>>(raw5, e4c, 1048576L);
    hipMemsetAsync(sums, 0, 4096, stream);
    bn_sums<<<256, 256, 0, stream>>>(e4c, sums, 131072L, 512);
    bn_fin<<<2, 256, 0, stream>>>(sums, g5, b5, sc, sh, 512, 1.f / 2048.f);
    bn_apply_t<true><<<dim3(32, 8), 256, 0, stream>>>(e4c, sc, sh, enc4, 512, 64, 32);

    // ---- L6: plain GEMM on CL enc4 (split-K 16)
    hipMemsetAsync(raw6, 0, 262144, stream);
    igemm<64, 0, 2><<<dim3(1, 8, 16), 256, 0, stream>>>(
        e4c, w6p, raw6, 128, 512, 8192, 512,
        0, 0, 0, 0, 1, 1, 1, 1, 1, 1, 0, 0, 0, 1, 1, 1);
    f2bk<<<256, 256, 0, stream>>>(raw6, e5c, 65536L);
    hipMemsetAsync(sums, 0, 4096, stream);
    bn_sums<<<256, 256, 0, stream>>>(e5c, sums, 8192L, 512);
    bn_fin<<<2, 256, 0, stream>>>(sums, g6, b6, sc, sh, 512, 1.f / 128.f);
    bn_apply_t<true><<<dim3(2, 8), 256, 0, stream>>>(e5c, sc, sh, enc5, 512, 64, 2);
}

// Round 4
// 650.165 us; speedup vs baseline: 12.8143x; 1.2458x over previous
//
#include <hip/hip_runtime.h>
#include <hip/hip_bf16.h>
#include <cstdint>

typedef short bf16x8 __attribute__((ext_vector_type(8)));
typedef float f32x4 __attribute__((ext_vector_type(4)));

__device__ __forceinline__ float lrelu_f(float y) { return y >= 0.f ? y : 0.2f * y; }
__device__ __forceinline__ float b2f(unsigned short u) {
    union { unsigned int i; float f; } v; v.i = ((unsigned int)u) << 16; return v.f;
}
__device__ __forceinline__ unsigned short f2b(float f) {
    union { unsigned int i; float f; } v; v.f = f;
    unsigned int r = v.i + 0x7FFFu + ((v.i >> 16) & 1u);
    return (unsigned short)(r >> 16);
}

// ---------------------------------------------------------------------------
// x (fp32 NCDHW [64][3][8][128][128]) -> bf16 CL [64][8][128][128][4] (c pad 3->4)
// ---------------------------------------------------------------------------
__global__ __launch_bounds__(256) void xin_cl_k(const float* __restrict__ x,
                                                unsigned short* __restrict__ xc)
{
    int i = blockIdx.x * 256 + threadIdx.x;       // exactly 33554432 threads
    int c = i & 3, w = (i >> 2) & 127, h = (i >> 9) & 127, d = (i >> 16) & 7, b = i >> 19;
    float v = (c < 3) ? x[(((size_t)b * 3 + c) * 8 + d) * 16384 + h * 128 + w] : 0.f;
    xc[i] = f2b(v);
}

// W fp32 [O][Cin][Tap] -> bf16 [O][Tap][Cip] (c padded)
__global__ __launch_bounds__(256) void repack_w(const float* __restrict__ w,
                                                unsigned short* __restrict__ wp,
                                                int Cin, int Tap, int Cip, long total)
{
    long i = (long)blockIdx.x * 256 + threadIdx.x;
    if (i >= total) return;
    int c = (int)(i % Cip);
    long t1 = i / Cip;
    int t = (int)(t1 % Tap);
    long o = t1 / Tap;
    wp[i] = (c < Cin) ? f2b(w[((size_t)o * Cin + c) * Tap + t]) : (unsigned short)0;
}

__global__ __launch_bounds__(256) void f2bk(const float* __restrict__ in,
                                            unsigned short* __restrict__ o, long n)
{
    long i = (long)blockIdx.x * 256 + threadIdx.x;
    if (i < n) o[i] = f2b(in[i]);
}

// ---------------------------------------------------------------------------
// Implicit-GEMM MFMA kernel. C[M][N] = A[M][K] * Bw[N][K]^T, bf16 in, fp32 acc.
// Tile 128 x BN, 4 waves, K-chunk 32, mfma_f32_16x16x32_bf16.
// AMODE 0: A is plain row-major bf16 [M][K]
// AMODE 1: A is CL activations; K order [tap][c], Ci%32==0, row=(b,od,oh,ow);
//          split-K supported (k0 = blockIdx.z*klen, must be multiple of 32)
// AMODE 2: conv1 special: 4x4x4 kernel, Cip=4, K order [tap][c4]
// EPI 0: bf16 store; EPI 1: fp32 store; EPI 2: fp32 atomicAdd; EPI 3: lrelu+bf16
// ---------------------------------------------------------------------------
template<int BN, int AMODE, int EPI>
__global__ __launch_bounds__(256) void igemm(
    const unsigned short* __restrict__ A, const unsigned short* __restrict__ Bw,
    void* __restrict__ Cout,
    int M, int N, int K, int klen,
    int Ci, int Di, int Hi, int Wi,
    int kd, int kh, int kw,
    int sd, int sh_, int sw_, int pd, int ph_, int pw_,
    int Do, int Ho, int Wo)
{
    constexpr int NF = BN / 32;
    constexpr int WN = 16 * NF;
    constexpr int NBU = (BN * 4 + 255) / 256;
    __shared__ __align__(16) unsigned short As[4][128][8];
    __shared__ __align__(16) unsigned short Bs[4][BN][8];
    const int tid = threadIdx.x;
    const int m0 = blockIdx.x * 128;
    const int n0 = blockIdx.y * BN;
    const int k0 = blockIdx.z * klen;
    const int kend = min(K, k0 + klen);

    // B staging precompute
    size_t bsrc[NBU];
    unsigned short* bdst[NBU];
#pragma unroll
    for (int i = 0; i < NBU; ++i) {
        int u = tid + i * 256;
        int row = u >> 2, s = u & 3;
        if (BN * 4 >= 256 || u < BN * 4) {
            bsrc[i] = (size_t)(n0 + row) * K + s * 8;
            bdst[i] = &Bs[s][row][0];
        }
    }

    // A staging precompute
    constexpr int NAU = (AMODE == 2) ? 4 : 2;
    size_t asz[2];
    int asrc[NAU];
    unsigned long long amask[NAU];
    unsigned short* adst[NAU];

    if constexpr (AMODE == 0) {
#pragma unroll
        for (int i = 0; i < 2; ++i) {
            int u = tid + i * 256;
            int r = u >> 2, s = u & 3;
            asz[i] = (size_t)(m0 + r) * K + s * 8;
            adst[i] = &As[s][r][0];
        }
    } else {
#pragma unroll
        for (int i = 0; i < NAU; ++i) {
            int u = tid + i * 256;
            int r = (AMODE == 2) ? (u >> 3) : (u >> 2);
            int m = m0 + r;
            int ow = m % Wo; int t1 = m / Wo;
            int oh = t1 % Ho; t1 /= Ho;
            int od = t1 % Do; int b = t1 / Do;
            int id0 = od * sd - pd, ih0 = oh * sh_ - ph_, iw0 = ow * sw_ - pw_;
            unsigned long long xm = 0ull, yx = 0ull, mask = 0ull;
            for (int p = 0; p < kw; ++p) if ((unsigned)(iw0 + p) < (unsigned)Wi) xm |= 1ull << p;
            for (int p = 0; p < kh; ++p) if ((unsigned)(ih0 + p) < (unsigned)Hi) yx |= xm << (p * kw);
            for (int p = 0; p < kd; ++p) if ((unsigned)(id0 + p) < (unsigned)Di) mask |= yx << (p * kh * kw);
            amask[i] = mask;
            int bsp = ((b * Di + id0) * Hi + ih0) * Wi + iw0;
            if constexpr (AMODE == 1) {
                int s = u & 3;
                asrc[i] = bsp * Ci + s * 8;
                adst[i] = &As[s][r][0];
            } else {
                int j = u & 7;
                asrc[i] = (bsp + (j >> 2) * Wi + (j & 3)) * 4;
                adst[i] = &As[j >> 1][r][(j & 1) * 4];
            }
        }
    }

    f32x4 acc[4][NF];
#pragma unroll
    for (int i = 0; i < 4; ++i)
#pragma unroll
        for (int j = 0; j < NF; ++j) acc[i][j] = (f32x4){0.f, 0.f, 0.f, 0.f};

    const int lane = tid & 63, wv = tid >> 6;
    const int wm = wv >> 1, wn = wv & 1;
    const int kg = lane >> 4, fr = lane & 15;

    // uniform k-walk state (AMODE 1), initialized from k0 for split-K
    int c0 = 0, kx = 0, ky = 0, tap = 0, doff = 0;
    if constexpr (AMODE == 1) {
        c0 = k0 % Ci;
        tap = k0 / Ci;
        kx = tap % kw;
        int t2 = tap / kw;
        ky = t2 % kh;
        int kz = t2 / kh;
        doff = (kz * Hi + ky) * Wi + kx;
    }

    for (int k = k0; k < kend; k += 32) {
        // ---- B stage
#pragma unroll
        for (int i = 0; i < NBU; ++i)
            if (BN * 4 >= 256 || tid + i * 256 < BN * 4) {
                uint4 v = *(const uint4*)&Bw[bsrc[i] + k];
                *(uint4*)bdst[i] = v;
            }
        // ---- A stage
        if constexpr (AMODE == 0) {
#pragma unroll
            for (int i = 0; i < 2; ++i) {
                uint4 v = *(const uint4*)&A[asz[i] + k];
                *(uint4*)adst[i] = v;
            }
        } else if constexpr (AMODE == 1) {
            int dofe = doff * Ci + c0;
#pragma unroll
            for (int i = 0; i < 2; ++i) {
                uint4 v = {0u, 0u, 0u, 0u};
                if ((amask[i] >> tap) & 1ull)
                    v = *(const uint4*)&A[(size_t)(asrc[i] + dofe)];
                *(uint4*)adst[i] = v;
            }
        } else {
            int kz = k >> 6;
            int U4 = (kz * (Hi * Wi) + ((k >> 5) & 1) * 2 * Wi) * 4;
            int tap0 = k >> 2;
#pragma unroll
            for (int i = 0; i < 4; ++i) {
                int j = (tid + i * 256) & 7;
                uint2 v = {0u, 0u};
                if ((amask[i] >> (tap0 + j)) & 1ull)
                    v = *(const uint2*)&A[(size_t)(asrc[i] + U4)];
                *(uint2*)adst[i] = v;
            }
        }
        __syncthreads();
        bf16x8 af[4], bfr[NF];
#pragma unroll
        for (int mi = 0; mi < 4; ++mi)
            af[mi] = *(const bf16x8*)&As[kg][wm * 64 + mi * 16 + fr][0];
#pragma unroll
        for (int ni = 0; ni < NF; ++ni)
            bfr[ni] = *(const bf16x8*)&Bs[kg][wn * WN + ni * 16 + fr][0];
#pragma unroll
        for (int mi = 0; mi < 4; ++mi)
#pragma unroll
            for (int ni = 0; ni < NF; ++ni)
                acc[mi][ni] = __builtin_amdgcn_mfma_f32_16x16x32_bf16(af[mi], bfr[ni], acc[mi][ni], 0, 0, 0);
        __syncthreads();
        if constexpr (AMODE == 1) {
            c0 += 32;
            if (c0 >= Ci) {
                c0 = 0; ++tap; ++kx; ++doff;
                if (kx == kw) {
                    kx = 0; doff += Wi - kw; ++ky;
                    if (ky == kh) { ky = 0; doff += (Hi - kh) * Wi; }
                }
            }
        }
    }
    // ---- epilogue: D row=(lane>>4)*4+reg, col=lane&15
    const int rb = m0 + wm * 64 + (lane >> 4) * 4;
    const int cb = n0 + wn * WN + fr;
#pragma unroll
    for (int mi = 0; mi < 4; ++mi)
#pragma unroll
        for (int ni = 0; ni < NF; ++ni)
#pragma unroll
            for (int rg = 0; rg < 4; ++rg) {
                size_t idx = (size_t)(rb + mi * 16 + rg) * N + cb + ni * 16;
                float vv = acc[mi][ni][rg];
                if constexpr (EPI == 0) ((unsigned short*)Cout)[idx] = f2b(vv);
                else if constexpr (EPI == 1) ((float*)Cout)[idx] = vv;
                else if constexpr (EPI == 2) atomicAdd((float*)Cout + idx, vv);
                else ((unsigned short*)Cout)[idx] = f2b(lrelu_f(vv));
            }
}

// ---------------------------------------------------------------------------
// BN partial sums over bf16 CL [Mrows][C] -> sums[0..C)=Σx, sums[C..2C)=Σx²
// ---------------------------------------------------------------------------
__global__ __launch_bounds__(256) void bn_sums(const unsigned short* __restrict__ x,
                                               float* __restrict__ sums,
                                               long totalSlots, int C)
{
    const int tid = threadIdx.x;
    long gid = (long)blockIdx.x * 256 + tid;
    long stride = (long)gridDim.x * 256;     // stride*8 % C == 0 for C in {32..512}
    float s1[8], s2[8];
#pragma unroll
    for (int j = 0; j < 8; ++j) { s1[j] = 0.f; s2[j] = 0.f; }
    for (long s = gid; s < totalSlots; s += stride) {
        uint4 v = *(const uint4*)&x[s * 8];
        const unsigned short* pv = (const unsigned short*)&v;
#pragma unroll
        for (int j = 0; j < 8; ++j) { float f = b2f(pv[j]); s1[j] += f; s2[j] += f * f; }
    }
    __shared__ float r1[2048], r2[2048];
#pragma unroll
    for (int j = 0; j < 8; ++j) { r1[tid * 8 + j] = s1[j]; r2[tid * 8 + j] = s2[j]; }
    __syncthreads();
    int G = C >> 3;
    for (int c = tid; c < C; c += 256) {
        int grp = c >> 3, j = c & 7;
        float a = 0.f, b = 0.f;
        for (int th = grp; th < 256; th += G) { a += r1[th * 8 + j]; b += r2[th * 8 + j]; }
        atomicAdd(&sums[c], a);
        atomicAdd(&sums[C + c], b);
    }
}

__global__ __launch_bounds__(256) void bn_fin(const float* __restrict__ sums,
                                              const float* __restrict__ g, const float* __restrict__ bt,
                                              float* __restrict__ sc, float* __restrict__ sh,
                                              int C, float invcnt)
{
    int c = blockIdx.x * 256 + threadIdx.x;
    if (c >= C) return;
    float mean = sums[c] * invcnt;
    float var = sums[C + c] * invcnt - mean * mean;
    float rs = rsqrtf(var + 1e-5f);
    float scl = g[c] * rs;
    sc[c] = scl;
    sh[c] = bt[c] - mean * scl;
}

// ---------------------------------------------------------------------------
// BN-apply + lrelu + NCDHW transpose.
// MODE 1: BN+lrelu, write back bf16 CL in place, emit fp32 NCDHW
// MODE 0: transpose-only (x already final; no write-back)
// Tile: 64 rows x TC channels. Grid (Mrows/64, C/TC). TC in {32,64}.
// ---------------------------------------------------------------------------
template<int MODE>
__global__ __launch_bounds__(256) void bn_apply_t(
    unsigned short* __restrict__ x, const float* __restrict__ sc, const float* __restrict__ sh,
    float* __restrict__ outN, int C, int TC, int S)
{
    __shared__ __align__(16) float T[64][68];
    const int tid = threadIdx.x;
    const long m0 = (long)blockIdx.x * 64;
    const int c0 = blockIdx.y * TC;
    const int spr = TC >> 3;                  // 16B slots per row: 4 or 8
    const int lg = (spr == 8) ? 3 : 2;
    const int tot = 64 * spr;
    for (int u = tid; u < tot; u += 256) {
        int r = u >> lg, sl = u & (spr - 1);
        size_t idx = (size_t)(m0 + r) * C + c0 + sl * 8;
        uint4 v = *(uint4*)&x[idx];
        unsigned short* pv = (unsigned short*)&v;
#pragma unroll
        for (int j = 0; j < 8; ++j) {
            int c = c0 + sl * 8 + j;
            float f = b2f(pv[j]);
            if (MODE == 1) {
                f = lrelu_f(f * sc[c] + sh[c]);
                pv[j] = f2b(f);
            }
            T[sl * 8 + j][r] = f;
        }
        if (MODE == 1) *(uint4*)&x[idx] = v;
    }
    __syncthreads();
    const int tpc = 256 / TC;                 // threads per column
    const int rpt = 64 / tpc;
    int cl = tid / tpc;
    int r0 = (tid % tpc) * rpt;
    int c = c0 + cl;
    if ((S & 63) == 0) {
        long b = m0 / S;
        long s0 = m0 - b * S;
        float* op = outN + ((size_t)b * C + c) * S + s0 + r0;
        for (int r = 0; r < rpt; r += 4)
            *(float4*)(op + r) = *(float4*)&T[cl][r0 + r];
    } else {
        for (int r = 0; r < rpt; ++r) {
            long m = m0 + r0 + r;
            long b = m / S, s = m - b * S;
            outN[((size_t)b * C + c) * S + s] = T[cl][r0 + r];
        }
    }
}

// ---------------------------------------------------------------------------
// Deformable trilinear sampling: block per (b, s), s in 32 output positions.
// x: enc3 CL bf16 [64][128 sp][256]; off: fp32 [2048][192]; val bf16 [2048][16*256]
// val[m][tap*256 + c]
// ---------------------------------------------------------------------------
__global__ __launch_bounds__(256) void deform_val(
    const unsigned short* __restrict__ xcl, const float* __restrict__ offc,
    unsigned short* __restrict__ val)
{
    int bs = blockIdx.x;
    int b = bs >> 5, s = bs & 31;
    int od = s >> 4, oh = (s >> 2) & 3, ow = s & 3;
    __shared__ float cw[64][8];
    __shared__ int cidx[64][8];
    int tid = threadIdx.x;
    if (tid < 64) {
        int gk = tid, k = gk & 15;
        int ky = k >> 2, kx = k & 3;
        const float* op = offc + (size_t)bs * 192 + gk * 3;
        float pz = op[0] + (float)od;
        float py = op[1] + (float)(oh * 2 - 1 + ky);
        float px = op[2] + (float)(ow * 2 - 1 + kx);
        float z0 = floorf(pz), y0 = floorf(py), x0 = floorf(px);
        float fz = pz - z0, fy = py - y0, fx = px - x0;
#pragma unroll
        for (int ci = 0; ci < 8; ++ci) {
            int cz = ci >> 2, cy = (ci >> 1) & 1, cx = ci & 1;
            float zc = z0 + cz, yc = y0 + cy, xc = x0 + cx;
            bool ok = zc >= 0.f && zc <= 1.f && yc >= 0.f && yc <= 7.f && xc >= 0.f && xc <= 7.f;
            int zi = min(max((int)zc, 0), 1);
            int yi = min(max((int)yc, 0), 7);
            int xi = min(max((int)xc, 0), 7);
            float wz = cz ? fz : 1.f - fz;
            float wy = cy ? fy : 1.f - fy;
            float wx = cx ? fx : 1.f - fx;
            cw[gk][ci] = ok ? wz * wy * wx : 0.f;
            cidx[gk][ci] = (zi * 8 + yi) * 8 + xi;
        }
    }
    __syncthreads();
    const unsigned short* xb = xcl + (size_t)b * 128 * 256;
    unsigned short* vo = val + (size_t)bs * 4096;
    for (int j = tid; j < 4096; j += 256) {
        int c = j & 255, tap = j >> 8;
        int gk = ((c >> 6) << 4) | tap;
        float v = 0.f;
#pragma unroll
        for (int i = 0; i < 8; ++i)
            v += cw[gk][i] * b2f(xb[(size_t)cidx[gk][i] * 256 + c]);
        vo[j] = f2b(v);
    }
}

// ---------------------------------------------------------------------------
extern "C" void kernel_launch(void* const* d_in, const int* in_sizes, int n_in,
                              void* d_out, int out_size, void* d_ws, size_t ws_size,
                              hipStream_t stream)
{
    (void)in_sizes; (void)n_in; (void)out_size; (void)ws_size;
    const float* x     = (const float*)d_in[0];
    const float* w1    = (const float*)d_in[1];
    const float* w2    = (const float*)d_in[2];
    const float* w3    = (const float*)d_in[3];
    const float* w4    = (const float*)d_in[4];
    const float* w_off = (const float*)d_in[5];
    const float* w5    = (const float*)d_in[6];
    const float* w6    = (const float*)d_in[7];
    const float* g2 = (const float*)d_in[8];  const float* b2 = (const float*)d_in[9];
    const float* g3 = (const float*)d_in[10]; const float* b3 = (const float*)d_in[11];
    const float* g4 = (const float*)d_in[12]; const float* b4 = (const float*)d_in[13];
    const float* g5 = (const float*)d_in[14]; const float* b5 = (const float*)d_in[15];
    const float* g6 = (const float*)d_in[16]; const float* b6 = (const float*)d_in[17];

    float* out = (float*)d_out;
    float* enc0 = out;
    float* enc1 = out + 33554432;
    float* enc2 = out + 46137344;
    float* enc3 = out + 50331648;
    float* enc4 = out + 52428800;
    float* enc5 = out + 53477376;

    // workspace layout (needs ~103 MiB)
    char* W = (char*)d_ws;
    unsigned short* w1p  = (unsigned short*)(W + 0);
    unsigned short* w2p  = (unsigned short*)(W + 16384);
    unsigned short* w3p  = (unsigned short*)(W + 147456);
    unsigned short* w4p  = (unsigned short*)(W + 671744);
    unsigned short* wofp = (unsigned short*)(W + 1720320);
    unsigned short* w5p  = (unsigned short*)(W + 3293184);
    unsigned short* w6p  = (unsigned short*)(W + 7487488);
    float* sums          = (float*)(W + 15876096);
    float* sc            = (float*)(W + 15880192);
    float* sh            = (float*)(W + 15882240);
    float* offc          = (float*)(W + 15884288);
    unsigned short* xcl  = (unsigned short*)(W + 17457152);   // dies after conv1
    unsigned short* e1c  = (unsigned short*)(W + 17457152);   // reuses xcl region
    unsigned short* e2c  = (unsigned short*)(W + 42622976);
    unsigned short* e3c  = (unsigned short*)(W + 51011584);
    unsigned short* e0c  = (unsigned short*)(W + 84566016);   // dies after conv2
    unsigned short* valb = (unsigned short*)(W + 84566016);   // reuses e0c region
    float* raw5          = (float*)(W + 101343232);
    unsigned short* e4c  = (unsigned short*)(W + 105537536);
    float* raw6          = (float*)(W + 107634688);
    unsigned short* e5c  = (unsigned short*)(W + 107896832);

    // ---- prep: input + weight repacks to bf16
    xin_cl_k<<<131072, 256, 0, stream>>>(x, xcl);
    repack_w<<<32, 256, 0, stream>>>(w1, w1p, 3, 64, 4, 8192L);
    repack_w<<<256, 256, 0, stream>>>(w2, w2p, 32, 32, 32, 65536L);
    repack_w<<<1024, 256, 0, stream>>>(w3, w3p, 64, 32, 64, 262144L);
    repack_w<<<2048, 256, 0, stream>>>(w4, w4p, 128, 16, 128, 524288L);
    repack_w<<<3072, 256, 0, stream>>>(w_off, wofp, 256, 16, 256, 786432L);
    repack_w<<<8192, 256, 0, stream>>>(w5, w5p, 256, 16, 256, 2097152L);
    repack_w<<<16384, 256, 0, stream>>>(w6, w6p, 512, 16, 512, 4194304L);

    // ---- L1: conv1 (4x4x4 s2 p1) -> e0c (lrelu fused in epilogue); NCDHW out
    igemm<32, 2, 3><<<dim3(8192, 1, 1), 256, 0, stream>>>(
        xcl, w1p, e0c, 1048576, 32, 256, 256,
        4, 8, 128, 128, 4, 4, 4, 2, 2, 2, 1, 1, 1, 4, 64, 64);
    bn_apply_t<0><<<dim3(16384, 1), 256, 0, stream>>>(e0c, nullptr, nullptr, enc0, 32, 32, 16384);

    // ---- L2
    igemm<64, 1, 0><<<dim3(1536, 1, 1), 256, 0, stream>>>(
        e0c, w2p, e1c, 196608, 64, 1024, 1024,
        32, 4, 64, 64, 2, 4, 4, 1, 2, 2, 0, 1, 1, 3, 32, 32);
    hipMemsetAsync(sums, 0, 4096, stream);
    bn_sums<<<256, 256, 0, stream>>>(e1c, sums, 1572864L, 64);
    bn_fin<<<1, 256, 0, stream>>>(sums, g2, b2, sc, sh, 64, 1.f / 196608.f);
    bn_apply_t<1><<<dim3(3072, 1), 256, 0, stream>>>(e1c, sc, sh, enc1, 64, 64, 3072);

    // ---- L3
    igemm<128, 1, 0><<<dim3(256, 1, 1), 256, 0, stream>>>(
        e1c, w3p, e2c, 32768, 128, 2048, 2048,
        64, 3, 32, 32, 2, 4, 4, 1, 2, 2, 0, 1, 1, 2, 16, 16);
    hipMemsetAsync(sums, 0, 4096, stream);
    bn_sums<<<256, 256, 0, stream>>>(e2c, sums, 524288L, 128);
    bn_fin<<<1, 256, 0, stream>>>(sums, g3, b3, sc, sh, 128, 1.f / 32768.f);
    bn_apply_t<1><<<dim3(512, 2), 256, 0, stream>>>(e2c, sc, sh, enc2, 128, 64, 512);

    // ---- L4 (BN=64, grid.y=4 -> 256 blocks)
    igemm<64, 1, 0><<<dim3(64, 4), 256, 0, stream>>>(
        e2c, w4p, e3c, 8192, 256, 2048, 2048,
        128, 2, 16, 16, 1, 4, 4, 1, 2, 2, 0, 1, 1, 2, 8, 8);
    hipMemsetAsync(sums, 0, 4096, stream);
    bn_sums<<<256, 256, 0, stream>>>(e3c, sums, 262144L, 256);
    bn_fin<<<1, 256, 0, stream>>>(sums, g4, b4, sc, sh, 256, 1.f / 8192.f);
    bn_apply_t<1><<<dim3(128, 4), 256, 0, stream>>>(e3c, sc, sh, enc3, 256, 64, 128);

    // ---- offset conv (no BN, no act), split-K 8 atomic into zeroed fp32 CL
    hipMemsetAsync(offc, 0, 1572864, stream);
    igemm<64, 1, 2><<<dim3(16, 3, 8), 256, 0, stream>>>(
        e3c, wofp, offc, 2048, 192, 4096, 512,
        256, 2, 8, 8, 1, 4, 4, 1, 2, 2, 0, 1, 1, 2, 4, 4);

    // ---- deformable sampling + GEMM (split-K 4, fp32 atomic)
    deform_val<<<2048, 256, 0, stream>>>(e3c, offc, valb);
    hipMemsetAsync(raw5, 0, 4194304, stream);
    igemm<64, 0, 2><<<dim3(16, 8, 4), 256, 0, stream>>>(
        valb, w5p, raw5, 2048, 512, 4096, 1024,
        0, 0, 0, 0, 1, 1, 1, 1, 1, 1, 0, 0, 0, 1, 1, 1);
    f2bk<<<4096, 256, 0, stream>>>(raw5, e4c, 1048576L);
    hipMemsetAsync(sums, 0, 4096, stream);
    bn_sums<<<256, 256, 0, stream>>>(e4c, sums, 131072L, 512);
    bn_fin<<<2, 256, 0, stream>>>(sums, g5, b5, sc, sh, 512, 1.f / 2048.f);
    bn_apply_t<1><<<dim3(32, 8), 256, 0, stream>>>(e4c, sc, sh, enc4, 512, 64, 32);

    // ---- L6: plain GEMM on CL enc4 (split-K 16)
    hipMemsetAsync(raw6, 0, 262144, stream);
    igemm<64, 0, 2><<<dim3(1, 8, 16), 256, 0, stream>>>(
        e4c, w6p, raw6, 128, 512, 8192, 512,
        0, 0, 0, 0, 1, 1, 1, 1, 1, 1, 0, 0, 0, 1, 1, 1);
    f2bk<<<256, 256, 0, stream>>>(raw6, e5c, 65536L);
    hipMemsetAsync(sums, 0, 4096, stream);
    bn_sums<<<256, 256, 0, stream>>>(e5c, sums, 8192L, 512);
    bn_fin<<<2, 256, 0, stream>>>(sums, g6, b6, sc, sh, 512, 1.f / 128.f);
    bn_apply_t<1><<<dim3(2, 8), 256, 0, stream>>>(e5c, sc, sh, enc5, 512, 64, 2);
}